// Round 4
// baseline (314.347 us; speedup 1.0000x reference)
//
#include <hip/hip_runtime.h>
#include <hip/hip_bf16.h>
#include <stdint.h>

// Problem constants
#define DD 1024
#define SS 2048
#define BB 4

typedef __bf16 bf16;
typedef __bf16 bf16x8 __attribute__((ext_vector_type(8)));
typedef __bf16 bf16x4 __attribute__((ext_vector_type(4)));
typedef float f32x4 __attribute__((ext_vector_type(4)));
typedef float f32x16 __attribute__((ext_vector_type(16)));

// ---- async global->LDS 16B copy (dest = wave-uniform base + lane*16) ----
__device__ __forceinline__ void gload_lds16(const bf16* g, bf16* l) {
  __builtin_amdgcn_global_load_lds(
      (const __attribute__((address_space(1))) void*)g,
      (__attribute__((address_space(3))) void*)l, 16, 0, 0);
}

// ---- fused fp32 -> bf16 conversions (x, R, E, Wv) in one dispatch -------
__global__ void cvt_all(const float* __restrict__ x, const float* __restrict__ R,
                        const float* __restrict__ E, const float* __restrict__ Wv,
                        bf16* __restrict__ xb, bf16* __restrict__ Rb,
                        bf16* __restrict__ Eb, bf16* __restrict__ Wvb) {
  int bid = blockIdx.x;
  const float* src;
  bf16* dst;
  int base;
  if (bid < 8192) { src = x; dst = xb; base = bid; }
  else if (bid < 9216) { src = R; dst = Rb; base = bid - 8192; }
  else if (bid < 10240) { src = E; dst = Eb; base = bid - 9216; }
  else { src = Wv; dst = Wvb; base = bid - 10240; }
  int i = (base * 256 + threadIdx.x) * 4;
  float4 v = *(const float4*)(src + i);
  bf16x4 o;
  o.x = (bf16)v.x; o.y = (bf16)v.y; o.z = (bf16)v.z; o.w = (bf16)v.w;
  *(bf16x4*)(dst + i) = o;
}

// ---- transpose+convert fp32 1024x1024 -> bf16 transposed (z: Wq/Wk) ----
__global__ void transpose_cvt(const float* __restrict__ Wq,
                              const float* __restrict__ Wk,
                              bf16* __restrict__ WqT, bf16* __restrict__ WkT) {
  const float* src = blockIdx.z ? Wk : Wq;
  bf16* dst = blockIdx.z ? WkT : WqT;
  __shared__ float tile[32][33];
  int x = blockIdx.x * 32 + threadIdx.x;  // src col
  int y0 = blockIdx.y * 32;
  for (int r = threadIdx.y; r < 32; r += 8)
    tile[r][threadIdx.x] = src[(y0 + r) * DD + x];
  __syncthreads();
  int dx = blockIdx.y * 32 + threadIdx.x;
  int dy0 = blockIdx.x * 32;
  for (int r = threadIdx.y; r < 32; r += 8)
    dst[(dy0 + r) * DD + dx] = (bf16)tile[threadIdx.x][r];
}

// ---- folded biases: bias[0:1024]=R@bq, [1024:2048]=E@bk, [2048:3072]=bv ----
__global__ void bias_fold(const float* __restrict__ R, const float* __restrict__ bq,
                          const float* __restrict__ E, const float* __restrict__ bk,
                          const float* __restrict__ bv, float* __restrict__ bias) {
  int e = blockIdx.x;  // 0..3071
  if (e >= 2048) { if (threadIdx.x == 0) bias[e] = bv[e - 2048]; return; }
  const float* M = (e < 1024) ? R : E;
  const float* bb = (e < 1024) ? bq : bk;
  int row = e & 1023;
  float s = 0.f;
  for (int f = threadIdx.x; f < DD; f += 256) s += M[row * DD + f] * bb[f];
  for (int o = 32; o >= 1; o >>= 1) s += __shfl_xor(s, o, 64);
  __shared__ float red[4];
  if ((threadIdx.x & 63) == 0) red[threadIdx.x >> 6] = s;
  __syncthreads();
  if (threadIdx.x == 0) bias[e] = red[0] + red[1] + red[2] + red[3];
}

// =================================================================
// BIG GEMM: 256x128 block tile, 128x64 wave tile, 32x32x16 MFMA.
// C = scale*(A @ B^T)(+bias). LDS rows are 64 elems (128 B); 16-B chunk c of
// row r stored at position c^(r&7) -> conflict-free b128 reads AND staging.
// MODE 0: C bf16 (+bias); if vTp and n0>=2048 (QKV V region) the tile is
//         written transposed to vT[b][d][s] via a 2-half LDS bounce.
// MODE 1: C fp32, causal (skip tiles with n0 > m0+255, mask, scale).
// =================================================================
template <int MODE>
__global__ __launch_bounds__(256, 2)
void gemm_big(const bf16* __restrict__ Ag, long lda, long sAb,
              const bf16* __restrict__ Bg, long ldb, long sBb,
              void* __restrict__ Cg, long ldc, long sCb,
              const float* __restrict__ bias, float scale, int K,
              bf16* __restrict__ vTp) {
  __shared__ __align__(16) bf16 As[256 * 64];  // 32 KB
  __shared__ __align__(16) bf16 Bs[128 * 64];  // 16 KB

  int bx = blockIdx.x, by = blockIdx.y, bz = blockIdx.z;
  if (MODE == 1 && bx > 2 * by + 1) return;  // fully-masked tile
  long m0 = (long)by * 256, n0 = (long)bx * 128;
  const bf16* A = Ag + (long)bz * sAb + m0 * lda;
  const bf16* Bp = Bg + (long)bz * sBb + n0 * ldb;

  int t = threadIdx.x;
  int w = t >> 6, l = t & 63;
  int lrow = l >> 3, lch = l & 7;
  int swz = (lch ^ lrow) * 8;  // staging source chunk offset (elements)
  int rl = l & 31, kh = l >> 5;
  int wm = w >> 1, wn = w & 1;

  f32x16 acc[4][2];
#pragma unroll
  for (int g = 0; g < 4; g++)
#pragma unroll
    for (int h = 0; h < 2; h++)
#pragma unroll
      for (int rr = 0; rr < 16; rr++) acc[g][h][rr] = 0.f;

  for (int k0 = 0; k0 < K; k0 += 64) {
    // stage: wave w -> A rows [w*64, w*64+64), B rows [w*32, w*32+32)
#pragma unroll
    for (int i = 0; i < 8; i++) {
      int r0 = w * 64 + i * 8;
      gload_lds16(A + (long)(r0 + lrow) * lda + k0 + swz, As + r0 * 64);
    }
#pragma unroll
    for (int i = 0; i < 4; i++) {
      int r0 = w * 32 + i * 8;
      gload_lds16(Bp + (long)(r0 + lrow) * ldb + k0 + swz, Bs + r0 * 64);
    }
    asm volatile("s_waitcnt vmcnt(0)" ::: "memory");
    __syncthreads();

#pragma unroll
    for (int kk = 0; kk < 4; kk++) {
      int pos = ((kk * 2 + kh) ^ (rl & 7)) * 8;
      bf16x8 af[4], bfr[2];
#pragma unroll
      for (int g = 0; g < 4; g++)
        af[g] = *(const bf16x8*)(As + (wm * 128 + g * 32 + rl) * 64 + pos);
#pragma unroll
      for (int h = 0; h < 2; h++)
        bfr[h] = *(const bf16x8*)(Bs + (wn * 64 + h * 32 + rl) * 64 + pos);
#pragma unroll
      for (int g = 0; g < 4; g++)
#pragma unroll
        for (int h = 0; h < 2; h++)
          acc[g][h] = __builtin_amdgcn_mfma_f32_32x32x16_bf16(
              af[g], bfr[h], acc[g][h], 0, 0, 0);
    }
    __syncthreads();
  }

  // 32x32 C/D layout: col = l&31, row = (rr&3) + 8*(rr>>2) + 4*(l>>5)
  if (MODE == 0) {
    if (vTp && n0 >= 2048) {
      // V region: transpose via LDS bounce (two 128-row halves, 32 KB each)
      int d0 = (int)n0 - 2048;
      int b = (int)(m0 >> 11);
      int s0 = (int)(m0 & 2047);
#pragma unroll
      for (int hs = 0; hs < 2; hs++) {
        if (wm == hs) {
#pragma unroll
          for (int g = 0; g < 4; g++)
#pragma unroll
            for (int h = 0; h < 2; h++) {
              int d = wn * 64 + h * 32 + rl;
              float bv_ = bias[n0 + d];
#pragma unroll
              for (int rr = 0; rr < 16; rr++) {
                int s = g * 32 + (rr & 3) + 8 * (rr >> 2) + 4 * kh;
                As[d * 128 + (s ^ ((d & 15) << 3))] = (bf16)(acc[g][h][rr] + bv_);
              }
            }
        }
        __syncthreads();
        int d = t >> 1, hc = t & 1;
        bf16* dst = vTp + (long)b * DD * SS + (long)(d0 + d) * SS + s0 + hs * 128;
#pragma unroll
        for (int j = 0; j < 8; j++) {
          int sb = hc * 64 + j * 8;
          bf16x8 v = *(const bf16x8*)(As + d * 128 + (sb ^ ((d & 15) << 3)));
          *(bf16x8*)(dst + sb) = v;
        }
        __syncthreads();
      }
    } else {
      bf16* C = (bf16*)Cg + (long)bz * sCb + m0 * ldc + n0;
#pragma unroll
      for (int g = 0; g < 4; g++)
#pragma unroll
        for (int h = 0; h < 2; h++) {
          int col = wn * 64 + h * 32 + rl;
          float bv_ = bias ? bias[n0 + col] : 0.f;
#pragma unroll
          for (int rr = 0; rr < 16; rr++) {
            int row = wm * 128 + g * 32 + (rr & 3) + 8 * (rr >> 2) + 4 * kh;
            C[(long)row * ldc + col] = (bf16)(acc[g][h][rr] + bv_);
          }
        }
    }
  } else {
    float* C = (float*)Cg + (long)bz * sCb + m0 * ldc + n0;
#pragma unroll
    for (int g = 0; g < 4; g++)
#pragma unroll
      for (int h = 0; h < 2; h++) {
        int col = wn * 64 + h * 32 + rl;
#pragma unroll
        for (int rr = 0; rr < 16; rr++) {
          int row = wm * 128 + g * 32 + (rr & 3) + 8 * (rr >> 2) + 4 * kh;
          if (n0 + col <= m0 + row)
            C[(long)row * ldc + col] = acc[g][h][rr] * scale;
        }
      }
  }
}

// ---- 128x128 GEMM (16x16x32), for small fold GEMM and causal P@V --------
// MODE 0: C bf16 (+bias). MODE 2: C fp32, K truncated at (by+1)*128.
template <int MODE>
__global__ __launch_bounds__(256, 4)
void gemm_bt(const bf16* __restrict__ Ag, long lda, long sAb,
             const bf16* __restrict__ Bg, long ldb, long sBb,
             void* __restrict__ Cg, long ldc, long sCb,
             const float* __restrict__ bias, float scale, int K) {
  __shared__ __align__(16) bf16 smem[16384];
  bf16* As = smem;
  bf16* Bs = smem + 8192;

  int bx = blockIdx.x, by = blockIdx.y, bz = blockIdx.z;
  long m0 = (long)by * 128, n0 = (long)bx * 128;
  const bf16* A = Ag + (long)bz * sAb + m0 * lda;
  const bf16* Bp = Bg + (long)bz * sBb + n0 * ldb;

  int t = threadIdx.x;
  int w = t >> 6, l = t & 63;
  int lr = l >> 2;
  int lc = (((l & 3) ^ (lr & 3)) * 8);
  int quad = l >> 4, ln = l & 15;
  int wm = w >> 1, wn = w & 1;
  int rdoff = ((quad ^ (ln & 3)) * 8);

  int Keff = (MODE == 2) ? (by + 1) * 128 : K;

  f32x4 acc[4][4];
#pragma unroll
  for (int i = 0; i < 4; i++)
#pragma unroll
    for (int j = 0; j < 4; j++) acc[i][j] = f32x4{0.f, 0.f, 0.f, 0.f};

  const bf16* a_base = As + (wm * 64 + ln) * 32 + rdoff;
  const bf16* b_base = Bs + (wn * 64 + ln) * 32 + rdoff;
  long arow0 = (long)(w * 16 + lr);

  for (int k0 = 0; k0 < Keff; k0 += 64) {
#pragma unroll
    for (int kk = 0; kk < 2; kk++) {
      int kc = k0 + kk * 32 + lc;
      gload_lds16(A + arow0 * lda + kc, As + kk * 4096 + w * 512);
      gload_lds16(A + (arow0 + 64) * lda + kc, As + kk * 4096 + 2048 + w * 512);
      gload_lds16(Bp + arow0 * ldb + kc, Bs + kk * 4096 + w * 512);
      gload_lds16(Bp + (arow0 + 64) * ldb + kc, Bs + kk * 4096 + 2048 + w * 512);
    }
    asm volatile("s_waitcnt vmcnt(0)" ::: "memory");
    __syncthreads();

#pragma unroll
    for (int kk = 0; kk < 2; kk++) {
      bf16x8 af[4], bfr[4];
#pragma unroll
      for (int i = 0; i < 4; i++) {
        af[i] = *(const bf16x8*)(a_base + kk * 4096 + i * 512);
        bfr[i] = *(const bf16x8*)(b_base + kk * 4096 + i * 512);
      }
#pragma unroll
      for (int i = 0; i < 4; i++)
#pragma unroll
        for (int j = 0; j < 4; j++)
          acc[i][j] = __builtin_amdgcn_mfma_f32_16x16x32_bf16(
              af[i], bfr[j], acc[i][j], 0, 0, 0);
    }
    __syncthreads();
  }

  if (MODE == 0) {
    bf16* C = (bf16*)Cg + (long)bz * sCb + m0 * ldc + n0;
#pragma unroll
    for (int i = 0; i < 4; i++) {
      int rb = wm * 64 + i * 16 + quad * 4;
#pragma unroll
      for (int j = 0; j < 4; j++) {
        int col = wn * 64 + j * 16 + ln;
        float bv_ = bias ? bias[n0 + col] : 0.f;
#pragma unroll
        for (int r = 0; r < 4; r++)
          C[(long)(rb + r) * ldc + col] = (bf16)(acc[i][j][r] + bv_);
      }
    }
  } else {
    float* C = (float*)Cg + (long)bz * sCb + m0 * ldc + n0;
#pragma unroll
    for (int i = 0; i < 4; i++) {
      int rb = wm * 64 + i * 16 + quad * 4;
#pragma unroll
      for (int j = 0; j < 4; j++) {
        int col = wn * 64 + j * 16 + ln;
#pragma unroll
        for (int r = 0; r < 4; r++)
          C[(long)(rb + r) * ldc + col] = acc[i][j][r];
      }
    }
  }
}

// ---- causal row softmax, in-place fp32 scores -> bf16 probs -------------
__global__ __launch_bounds__(256) void softmax_rows(float* __restrict__ scores) {
  long m = blockIdx.x;
  int i = (int)(m & (SS - 1));
  float* row = scores + m * SS;
  int t = threadIdx.x;
  int nvalid = i + 1;
  int base = t * 8;
  float x[8] = {0, 0, 0, 0, 0, 0, 0, 0};
  if (base < nvalid) {  // skip fully-masked chunks
    float4 v0 = *(const float4*)(row + base);
    float4 v1 = *(const float4*)(row + base + 4);
    x[0] = v0.x; x[1] = v0.y; x[2] = v0.z; x[3] = v0.w;
    x[4] = v1.x; x[5] = v1.y; x[6] = v1.z; x[7] = v1.w;
  }

  float mx = -INFINITY;
#pragma unroll
  for (int j = 0; j < 8; j++)
    if (base + j < nvalid) mx = fmaxf(mx, x[j]);
  for (int o = 32; o >= 1; o >>= 1) mx = fmaxf(mx, __shfl_xor(mx, o, 64));
  __shared__ float red[8];
  if ((t & 63) == 0) red[t >> 6] = mx;
  __syncthreads();
  mx = fmaxf(fmaxf(red[0], red[1]), fmaxf(red[2], red[3]));

  float e[8];
  float sum = 0.f;
#pragma unroll
  for (int j = 0; j < 8; j++) {
    e[j] = (base + j < nvalid) ? __expf(x[j] - mx) : 0.f;
    sum += e[j];
  }
  for (int o = 32; o >= 1; o >>= 1) sum += __shfl_xor(sum, o, 64);
  if ((t & 63) == 0) red[4 + (t >> 6)] = sum;
  __syncthreads();
  sum = red[4] + red[5] + red[6] + red[7];
  float inv = 1.f / sum;

  bf16x8 o8;
#pragma unroll
  for (int j = 0; j < 8; j++) o8[j] = (bf16)(e[j] * inv);
  *(bf16x8*)((bf16*)row + base) = o8;  // in-place: bf16 row in first half
}

extern "C" void kernel_launch(void* const* d_in, const int* in_sizes, int n_in,
                              void* d_out, int out_size, void* d_ws,
                              size_t ws_size, hipStream_t stream) {
  const float* x = (const float*)d_in[0];
  const float* R = (const float*)d_in[1];
  const float* E = (const float*)d_in[2];
  const float* Wq = (const float*)d_in[3];
  const float* bq = (const float*)d_in[4];
  const float* Wk = (const float*)d_in[5];
  const float* bk = (const float*)d_in[6];
  const float* Wv = (const float*)d_in[7];
  const float* bv = (const float*)d_in[8];
  float* out = (float*)d_out;

  char* ws = (char*)d_ws;
  // Layout (128 MiB total):
  //   qkv    @ 0       : 8192*3072 bf16 (V cols unused)   = 48 MiB
  //   vT     @ 48 MiB  : 4*1024*2048 bf16                 = 16 MiB
  //   scores @ 64 MiB  : 4*2048*2048 f32 (probs in-place) = 64 MiB
  // Prep buffers alias the scores region (dead before scores written):
  bf16* qkv = (bf16*)ws;
  bf16* vT = (bf16*)(ws + 50331648);
  float* scores = (float*)(ws + 67108864);
  char* sr = ws + 67108864;
  bf16* xb = (bf16*)sr;                   // 16 MiB
  bf16* Rb = (bf16*)(sr + 16777216);      // 2 MiB  (Rb|Eb adjacent: batched)
  bf16* WqT = (bf16*)(sr + 20971520);     // 2 MiB  (WqT|WkT adjacent)
  bf16* wcat = (bf16*)(sr + 25165824);    // 6 MiB (Wq'|Wk'|Wv)
  float* bias = (float*)(sr + 31457280);  // 12 KiB
  bf16* Eb = Rb + 1024 * 1024;
  bf16* WkT = WqT + 1024 * 1024;

  // 1) conversions (fused) + weight transposes (batched) + bias fold
  cvt_all<<<11264, 256, 0, stream>>>(x, R, E, Wv, xb, Rb, Eb, wcat + 2048 * DD);
  transpose_cvt<<<dim3(32, 32, 2), dim3(32, 8), 0, stream>>>(Wq, Wk, WqT, WkT);
  bias_fold<<<3072, 256, 0, stream>>>(R, bq, E, bk, bv, bias);

  // 2) fold weights (batched bz=2): Wq' = R@Wq ; Wk' = E@Wk
  gemm_bt<0><<<dim3(8, 8, 2), 256, 0, stream>>>(
      Rb, DD, 1024 * 1024, WqT, DD, 1024 * 1024, wcat, DD, 1024 * 1024,
      nullptr, 1.f, DD);

  // 3) fused QKV (M=8192, N=3072, K=1024); V-tiles written transposed to vT
  gemm_big<0><<<dim3(24, 32, 1), 256, 0, stream>>>(xb, DD, 0, wcat, DD, 0, qkv,
                                                   3072, 0, bias, 1.f, DD, vT);

  // 4) causal scores: S = (Q @ K^T)/32, lower-tri tiles only, fp32
  gemm_big<1><<<dim3(16, 8, BB), 256, 0, stream>>>(
      qkv, 3072, (long)SS * 3072, qkv + 1024, 3072, (long)SS * 3072, scores,
      SS, (long)SS * SS, nullptr, 0.03125f, DD, nullptr);

  // 5) softmax rows -> bf16 probs in place
  softmax_rows<<<BB * SS, 256, 0, stream>>>(scores);

  // 6) out = P @ V : A=probs (lda=4096 bf16), B=vT, K truncated causally
  gemm_bt<2><<<dim3(8, 16, BB), 256, 0, stream>>>(
      (const bf16*)scores, 4096, (long)SS * 4096, vT, SS, (long)DD * SS, out,
      DD, (long)SS * DD, nullptr, 1.f, SS);
}

// Round 5
// 308.771 us; speedup vs baseline: 1.0181x; 1.0181x over previous
//
#include <hip/hip_runtime.h>
#include <hip/hip_bf16.h>
#include <stdint.h>

// Problem constants
#define DD 1024
#define SS 2048
#define BB 4

typedef __bf16 bf16;
typedef __bf16 bf16x8 __attribute__((ext_vector_type(8)));
typedef __bf16 bf16x4 __attribute__((ext_vector_type(4)));
typedef float f32x4 __attribute__((ext_vector_type(4)));

// ---- async global->LDS 16B copy (dest = wave-uniform base + lane*16) ----
__device__ __forceinline__ void gload_lds16(const bf16* g, bf16* l) {
  __builtin_amdgcn_global_load_lds(
      (const __attribute__((address_space(1))) void*)g,
      (__attribute__((address_space(3))) void*)l, 16, 0, 0);
}

// ---- ALL preprocessing in ONE dispatch --------------------------------
// blocks [0,11264):    fp32->bf16 cvt of x, R, E, Wv
// blocks [11264,13312): transpose+cvt Wq -> WqT, Wk -> WkT
// blocks [13312,16384): bias fold (R@bq | E@bk | bv)
__global__ __launch_bounds__(256) void prep_all(
    const float* __restrict__ x, const float* __restrict__ R,
    const float* __restrict__ E, const float* __restrict__ Wv,
    const float* __restrict__ Wq, const float* __restrict__ Wk,
    const float* __restrict__ bq, const float* __restrict__ bk,
    const float* __restrict__ bv, bf16* __restrict__ xb,
    bf16* __restrict__ Rb, bf16* __restrict__ Eb, bf16* __restrict__ Wvb,
    bf16* __restrict__ WqT, bf16* __restrict__ WkT, float* __restrict__ bias) {
  int bid = blockIdx.x;
  int t = threadIdx.x;
  if (bid < 11264) {
    const float* src;
    bf16* dst;
    int base;
    if (bid < 8192) { src = x; dst = xb; base = bid; }
    else if (bid < 9216) { src = R; dst = Rb; base = bid - 8192; }
    else if (bid < 10240) { src = E; dst = Eb; base = bid - 9216; }
    else { src = Wv; dst = Wvb; base = bid - 10240; }
    int i = (base * 256 + t) * 4;
    float4 v = *(const float4*)(src + i);
    bf16x4 o;
    o.x = (bf16)v.x; o.y = (bf16)v.y; o.z = (bf16)v.z; o.w = (bf16)v.w;
    *(bf16x4*)(dst + i) = o;
  } else if (bid < 13312) {
    int r2 = bid - 11264;
    const float* src = (r2 >= 1024) ? Wk : Wq;
    bf16* dst = (r2 >= 1024) ? WkT : WqT;
    int rem = r2 & 1023;
    int bx = rem & 31, by = rem >> 5;
    __shared__ float tile[32][33];
    int tx = t & 31, ty = t >> 5;
    int xcol = bx * 32 + tx;
    int y0 = by * 32;
    for (int r = ty; r < 32; r += 8)
      tile[r][tx] = src[(y0 + r) * DD + xcol];
    __syncthreads();
    int dx = by * 32 + tx;
    int dy0 = bx * 32;
    for (int r = ty; r < 32; r += 8)
      dst[(dy0 + r) * DD + dx] = (bf16)tile[tx][r];
  } else {
    int e = bid - 13312;  // 0..3071
    if (e >= 2048) { if (t == 0) bias[e] = bv[e - 2048]; return; }
    const float* M = (e < 1024) ? R : E;
    const float* bb = (e < 1024) ? bq : bk;
    int row = e & 1023;
    float s = 0.f;
    for (int f = t; f < DD; f += 256) s += M[row * DD + f] * bb[f];
    for (int o = 32; o >= 1; o >>= 1) s += __shfl_xor(s, o, 64);
    __shared__ float red[4];
    if ((t & 63) == 0) red[t >> 6] = s;
    __syncthreads();
    if (t == 0) bias[e] = red[0] + red[1] + red[2] + red[3];
  }
}

// ---- generic bf16 GEMM: C = scale * (A @ B^T) (+bias), 128x128x64 tiles ----
// BK=64 as two 128x32 sub-tiles per barrier pair (32 MFMA per LDS drain).
// MODE 0: C bf16 (+bias). If vTp set and n0>=2048 (QKV V-region), the tile is
// written TRANSPOSED to vT[b][d][s] via an XOR-swizzled LDS bounce.
// MODE 1: C fp32, causal (skip upper tiles, mask diag, scale).
// MODE 2: C fp32, K-loop truncated at (by+1)*128.
template <int MODE>
__global__ __launch_bounds__(256, 4)
void gemm_bt(const bf16* __restrict__ Ag, long lda, long sAb,
             const bf16* __restrict__ Bg, long ldb, long sBb,
             void* __restrict__ Cg, long ldc, long sCb,
             const float* __restrict__ bias, float scale, int K,
             bf16* __restrict__ vTp) {
  __shared__ __align__(16) bf16 smem[16384];  // As | Bs ; reused for bounce
  bf16* As = smem;
  bf16* Bs = smem + 8192;

  int bx = blockIdx.x, by = blockIdx.y, bz = blockIdx.z;
  if (MODE == 1 && bx > by) return;  // strictly-upper tile: all masked
  long m0 = (long)by * 128, n0 = (long)bx * 128;
  const bf16* A = Ag + (long)bz * sAb + m0 * lda;
  const bf16* Bp = Bg + (long)bz * sBb + n0 * ldb;

  int t = threadIdx.x;
  int w = t >> 6, l = t & 63;
  int lr = l >> 2;
  int lc = (((l & 3) ^ (lr & 3)) * 8);  // swizzled source chunk
  int quad = l >> 4, ln = l & 15;
  int wm = w >> 1, wn = w & 1;
  int rdoff = ((quad ^ (ln & 3)) * 8);  // swizzled read offset

  int Keff = (MODE == 2) ? (by + 1) * 128 : K;

  f32x4 acc[4][4];
#pragma unroll
  for (int i = 0; i < 4; i++)
#pragma unroll
    for (int j = 0; j < 4; j++) acc[i][j] = f32x4{0.f, 0.f, 0.f, 0.f};

  const bf16* a_base = As + (wm * 64 + ln) * 32 + rdoff;
  const bf16* b_base = Bs + (wn * 64 + ln) * 32 + rdoff;
  long arow0 = (long)(w * 16 + lr);

  for (int k0 = 0; k0 < Keff; k0 += 64) {
#pragma unroll
    for (int kk = 0; kk < 2; kk++) {
      int kc = k0 + kk * 32 + lc;
      gload_lds16(A + arow0 * lda + kc, As + kk * 4096 + w * 512);
      gload_lds16(A + (arow0 + 64) * lda + kc, As + kk * 4096 + 2048 + w * 512);
      gload_lds16(Bp + arow0 * ldb + kc, Bs + kk * 4096 + w * 512);
      gload_lds16(Bp + (arow0 + 64) * ldb + kc, Bs + kk * 4096 + 2048 + w * 512);
    }
    asm volatile("s_waitcnt vmcnt(0)" ::: "memory");
    __syncthreads();

#pragma unroll
    for (int kk = 0; kk < 2; kk++) {
      bf16x8 af[4], bfr[4];
#pragma unroll
      for (int i = 0; i < 4; i++) {
        af[i] = *(const bf16x8*)(a_base + kk * 4096 + i * 512);
        bfr[i] = *(const bf16x8*)(b_base + kk * 4096 + i * 512);
      }
#pragma unroll
      for (int i = 0; i < 4; i++)
#pragma unroll
        for (int j = 0; j < 4; j++)
          acc[i][j] = __builtin_amdgcn_mfma_f32_16x16x32_bf16(
              af[i], bfr[j], acc[i][j], 0, 0, 0);
    }
    __syncthreads();
  }

  // epilogue: within each 16x16 tile, C row = quad*4 + r, col = ln
  if (MODE == 0) {
    if (vTp && n0 >= 2048) {
      // V-region: bounce through LDS, write transposed to vT[b][d][s].
      // Element (d,s) stored at smem[d*128 + (s ^ ((d&15)*8))] (bank-swizzle).
      int d0 = (int)n0 - 2048;
      int b = (int)(m0 >> 11);
      int s0 = (int)(m0 & 2047);
#pragma unroll
      for (int i = 0; i < 4; i++) {
        int sb = wm * 64 + i * 16 + quad * 4;
#pragma unroll
        for (int j = 0; j < 4; j++) {
          int d = wn * 64 + j * 16 + ln;
          float bv_ = bias[n0 + d];
#pragma unroll
          for (int r = 0; r < 4; r++)
            smem[d * 128 + ((sb + r) ^ (ln << 3))] = (bf16)(acc[i][j][r] + bv_);
        }
      }
      __syncthreads();
      int d = t >> 1, h = t & 1;
      bf16* dst = vTp + (long)b * DD * SS + (long)(d0 + d) * SS + s0 + h * 64;
#pragma unroll
      for (int j = 0; j < 8; j++) {
        int sbase = h * 64 + j * 8;
        bf16x8 v = *(const bf16x8*)(smem + d * 128 + (sbase ^ ((d & 15) << 3)));
        *(bf16x8*)(dst + j * 8) = v;
      }
    } else {
      bf16* C = (bf16*)Cg + (long)bz * sCb + m0 * ldc + n0;
#pragma unroll
      for (int i = 0; i < 4; i++) {
        int rb = wm * 64 + i * 16 + quad * 4;
#pragma unroll
        for (int j = 0; j < 4; j++) {
          int col = wn * 64 + j * 16 + ln;
          float bv_ = bias ? bias[n0 + col] : 0.f;
#pragma unroll
          for (int r = 0; r < 4; r++)
            C[(long)(rb + r) * ldc + col] = (bf16)(acc[i][j][r] + bv_);
        }
      }
    }
  } else {
    float* C = (float*)Cg + (long)bz * sCb + m0 * ldc + n0;
#pragma unroll
    for (int i = 0; i < 4; i++) {
      int rb = wm * 64 + i * 16 + quad * 4;
#pragma unroll
      for (int j = 0; j < 4; j++) {
        int col = wn * 64 + j * 16 + ln;
#pragma unroll
        for (int r = 0; r < 4; r++) {
          int row = rb + r;
          if (MODE == 1) {
            if (n0 + col <= m0 + row)
              C[(long)row * ldc + col] = acc[i][j][r] * scale;
          } else {
            C[(long)row * ldc + col] = acc[i][j][r];
          }
        }
      }
    }
  }
}

// ---- causal row softmax: ONE WAVE per row, no barriers, no LDS ----------
// 4 rows per block. Row m: valid cols j <= (m&2047). In-place fp32 -> bf16.
__global__ __launch_bounds__(256) void softmax_rows(float* __restrict__ scores) {
  long m = (long)blockIdx.x * 4 + (threadIdx.x >> 6);
  int l = threadIdx.x & 63;
  int nvalid = (int)(m & (SS - 1)) + 1;
  float* row = scores + m * SS;

  float xv[32];
  // chunk c covers [c*256, c*256+256); lane reads float4 at c*256 + l*4
#pragma unroll
  for (int c = 0; c < 8; c++) {
    int base = c * 256 + l * 4;
    float4 v = {0.f, 0.f, 0.f, 0.f};
    if (base < nvalid) v = *(const float4*)(row + base);
    xv[c * 4 + 0] = v.x; xv[c * 4 + 1] = v.y;
    xv[c * 4 + 2] = v.z; xv[c * 4 + 3] = v.w;
  }

  float mx = -INFINITY;
#pragma unroll
  for (int c = 0; c < 8; c++) {
    int base = c * 256 + l * 4;
#pragma unroll
    for (int j = 0; j < 4; j++)
      if (base + j < nvalid) mx = fmaxf(mx, xv[c * 4 + j]);
  }
  for (int o = 32; o >= 1; o >>= 1) mx = fmaxf(mx, __shfl_xor(mx, o, 64));

  float e[32];
  float sum = 0.f;
#pragma unroll
  for (int c = 0; c < 8; c++) {
    int base = c * 256 + l * 4;
#pragma unroll
    for (int j = 0; j < 4; j++) {
      float ev = (base + j < nvalid) ? __expf(xv[c * 4 + j] - mx) : 0.f;
      e[c * 4 + j] = ev;
      sum += ev;
    }
  }
  for (int o = 32; o >= 1; o >>= 1) sum += __shfl_xor(sum, o, 64);
  float inv = 1.f / sum;

  bf16* brow = (bf16*)row;
#pragma unroll
  for (int c = 0; c < 8; c++) {
    int base = c * 256 + l * 4;
    bf16x4 o4;
#pragma unroll
    for (int j = 0; j < 4; j++) o4[j] = (bf16)(e[c * 4 + j] * inv);
    *(bf16x4*)(brow + base) = o4;
  }
}

extern "C" void kernel_launch(void* const* d_in, const int* in_sizes, int n_in,
                              void* d_out, int out_size, void* d_ws,
                              size_t ws_size, hipStream_t stream) {
  const float* x = (const float*)d_in[0];
  const float* R = (const float*)d_in[1];
  const float* E = (const float*)d_in[2];
  const float* Wq = (const float*)d_in[3];
  const float* bq = (const float*)d_in[4];
  const float* Wk = (const float*)d_in[5];
  const float* bk = (const float*)d_in[6];
  const float* Wv = (const float*)d_in[7];
  const float* bv = (const float*)d_in[8];
  float* out = (float*)d_out;

  char* ws = (char*)d_ws;
  // Layout (128 MiB total):
  //   qkv    @ 0       : 8192*3072 bf16 (V cols unused)   = 48 MiB
  //   vT     @ 48 MiB  : 4*1024*2048 bf16                 = 16 MiB
  //   scores @ 64 MiB  : 4*2048*2048 f32 (probs in-place) = 64 MiB
  // Prep buffers alias the scores region (dead before scores written):
  bf16* qkv = (bf16*)ws;
  bf16* vT = (bf16*)(ws + 50331648);
  float* scores = (float*)(ws + 67108864);
  char* sr = ws + 67108864;
  bf16* xb = (bf16*)sr;                   // 16 MiB
  bf16* Rb = (bf16*)(sr + 16777216);      // 2 MiB  (Rb|Eb adjacent: batched)
  bf16* WqT = (bf16*)(sr + 20971520);     // 2 MiB  (WqT|WkT adjacent)
  bf16* wcat = (bf16*)(sr + 25165824);    // 6 MiB (Wq'|Wk'|Wv)
  float* bias = (float*)(sr + 31457280);  // 12 KiB
  bf16* Eb = Rb + 1024 * 1024;
  bf16* WkT = WqT + 1024 * 1024;

  // 1) all preprocessing (cvt x/R/E/Wv, transpose Wq/Wk, bias fold): 1 dispatch
  prep_all<<<16384, 256, 0, stream>>>(x, R, E, Wv, Wq, Wk, bq, bk, bv, xb, Rb,
                                      Eb, wcat + 2048 * DD, WqT, WkT, bias);

  // 2) fold weights (batched bz=2): Wq' = R@Wq ; Wk' = E@Wk
  gemm_bt<0><<<dim3(8, 8, 2), 256, 0, stream>>>(
      Rb, DD, 1024 * 1024, WqT, DD, 1024 * 1024, wcat, DD, 1024 * 1024,
      nullptr, 1.f, DD, nullptr);

  // 3) fused QKV (M=8192, N=3072, K=1024); V-tiles written transposed to vT
  gemm_bt<0><<<dim3(24, 64, 1), 256, 0, stream>>>(xb, DD, 0, wcat, DD, 0, qkv,
                                                  3072, 0, bias, 1.f, DD, vT);

  // 4) causal scores: S = (Q @ K^T)/32, lower-tri tiles only, fp32
  gemm_bt<1><<<dim3(16, 16, BB), 256, 0, stream>>>(
      qkv, 3072, (long)SS * 3072, qkv + 1024, 3072, (long)SS * 3072, scores,
      SS, (long)SS * SS, nullptr, 0.03125f, DD, nullptr);

  // 5) softmax rows -> bf16 probs in place (1 wave/row, 4 rows/block)
  softmax_rows<<<BB * SS / 4, 256, 0, stream>>>(scores);

  // 6) out = P @ V : A=probs (lda=4096 bf16), B=vT, K truncated causally
  gemm_bt<2><<<dim3(8, 16, BB), 256, 0, stream>>>(
      (const bf16*)scores, 4096, (long)SS * 4096, vT, SS, (long)DD * SS, out,
      DD, (long)SS * DD, nullptr, 1.f, SS, nullptr);
}

// Round 6
// 302.988 us; speedup vs baseline: 1.0375x; 1.0191x over previous
//
#include <hip/hip_runtime.h>
#include <hip/hip_bf16.h>
#include <stdint.h>
#include <math.h>

// Problem constants
#define DD 1024
#define SS 2048
#define BB 4

typedef __bf16 bf16;
typedef __bf16 bf16x8 __attribute__((ext_vector_type(8)));
typedef __bf16 bf16x4 __attribute__((ext_vector_type(4)));
typedef float f32x4 __attribute__((ext_vector_type(4)));

// ---- async global->LDS 16B copy (dest = wave-uniform base + lane*16) ----
__device__ __forceinline__ void gload_lds16(const bf16* g, bf16* l) {
  __builtin_amdgcn_global_load_lds(
      (const __attribute__((address_space(1))) void*)g,
      (__attribute__((address_space(3))) void*)l, 16, 0, 0);
}

// ---- ALL preprocessing in ONE dispatch --------------------------------
// blocks [0,11264):     fp32->bf16 cvt of x, R, E, Wv
// blocks [11264,13312): transpose+cvt Wq -> WqT, Wk -> WkT
// blocks [13312,16384): bias fold (R@bq | E@bk | bv)
// blocks [16384,16416): zero rowsums (8192 floats)
__global__ __launch_bounds__(256) void prep_all(
    const float* __restrict__ x, const float* __restrict__ R,
    const float* __restrict__ E, const float* __restrict__ Wv,
    const float* __restrict__ Wq, const float* __restrict__ Wk,
    const float* __restrict__ bq, const float* __restrict__ bk,
    const float* __restrict__ bv, bf16* __restrict__ xb,
    bf16* __restrict__ Rb, bf16* __restrict__ Eb, bf16* __restrict__ Wvb,
    bf16* __restrict__ WqT, bf16* __restrict__ WkT, float* __restrict__ bias,
    float* __restrict__ rowsums) {
  int bid = blockIdx.x;
  int t = threadIdx.x;
  if (bid < 11264) {
    const float* src;
    bf16* dst;
    int base;
    if (bid < 8192) { src = x; dst = xb; base = bid; }
    else if (bid < 9216) { src = R; dst = Rb; base = bid - 8192; }
    else if (bid < 10240) { src = E; dst = Eb; base = bid - 9216; }
    else { src = Wv; dst = Wvb; base = bid - 10240; }
    int i = (base * 256 + t) * 4;
    float4 v = *(const float4*)(src + i);
    bf16x4 o;
    o.x = (bf16)v.x; o.y = (bf16)v.y; o.z = (bf16)v.z; o.w = (bf16)v.w;
    *(bf16x4*)(dst + i) = o;
  } else if (bid < 13312) {
    int r2 = bid - 11264;
    const float* src = (r2 >= 1024) ? Wk : Wq;
    bf16* dst = (r2 >= 1024) ? WkT : WqT;
    int rem = r2 & 1023;
    int bx = rem & 31, by = rem >> 5;
    __shared__ float tile[32][33];
    int tx = t & 31, ty = t >> 5;
    int xcol = bx * 32 + tx;
    int y0 = by * 32;
    for (int r = ty; r < 32; r += 8)
      tile[r][tx] = src[(y0 + r) * DD + xcol];
    __syncthreads();
    int dx = by * 32 + tx;
    int dy0 = bx * 32;
    for (int r = ty; r < 32; r += 8)
      dst[(dy0 + r) * DD + dx] = (bf16)tile[tx][r];
  } else if (bid < 16384) {
    int e = bid - 13312;  // 0..3071
    if (e >= 2048) { if (t == 0) bias[e] = bv[e - 2048]; return; }
    const float* M = (e < 1024) ? R : E;
    const float* bb = (e < 1024) ? bq : bk;
    int row = e & 1023;
    float s = 0.f;
    for (int f = t; f < DD; f += 256) s += M[row * DD + f] * bb[f];
    for (int o = 32; o >= 1; o >>= 1) s += __shfl_xor(s, o, 64);
    __shared__ float red[4];
    if ((t & 63) == 0) red[t >> 6] = s;
    __syncthreads();
    if (t == 0) bias[e] = red[0] + red[1] + red[2] + red[3];
  } else {
    int idx = (bid - 16384) * 256 + t;  // 0..8191
    rowsums[idx] = 0.f;
  }
}

// ---- generic bf16 GEMM: C = scale * (A @ B^T) (+bias), 128x128x64 tiles ----
// BK=64 as two 128x32 sub-tiles per barrier pair (32 MFMA per LDS drain).
// MODE 0: C bf16 (+bias). If vTp set and n0>=2048 (QKV V-region), the tile is
//         written TRANSPOSED to vT[b][d][s] via an XOR-swizzled LDS bounce.
// MODE 1: causal scores with FUSED EXP: dense triangular grid (blockIdx.x
//         decodes to (bx<=by)); P~ = exp(scale*acc) (0 above diag) written as
//         bf16 via swizzled LDS bounce (vectorized); per-row sums of the
//         bf16-rounded P~ atomically added to rowsums[b*SS+row].
// MODE 2: P~ @ V with K truncated at (by+1)*128, by reversed (long-first);
//         epilogue divides by rowsums (softmax normalization folded here).
template <int MODE>
__global__ __launch_bounds__(256, 4)
void gemm_bt(const bf16* __restrict__ Ag, long lda, long sAb,
             const bf16* __restrict__ Bg, long ldb, long sBb,
             void* __restrict__ Cg, long ldc, long sCb,
             const float* __restrict__ bias, float scale, int K,
             bf16* __restrict__ vTp, float* __restrict__ rowsums) {
  __shared__ __align__(16) bf16 smem[16384];  // As | Bs ; reused for bounce
  bf16* As = smem;
  bf16* Bs = smem + 8192;

  int bx = blockIdx.x, by = blockIdx.y, bz = blockIdx.z;
  if (MODE == 1) {  // triangular decode: q -> (by, bx<=by)
    int q = bx;
    by = (int)((sqrtf(8.f * q + 1.f) - 1.f) * 0.5f);
    while ((by + 1) * (by + 2) / 2 <= q) by++;
    while (by * (by + 1) / 2 > q) by--;
    bx = q - by * (by + 1) / 2;
  }
  if (MODE == 2) by = 15 - by;  // longest K strips dispatch first
  long m0 = (long)by * 128, n0 = (long)bx * 128;
  const bf16* A = Ag + (long)bz * sAb + m0 * lda;
  const bf16* Bp = Bg + (long)bz * sBb + n0 * ldb;

  int t = threadIdx.x;
  int w = t >> 6, l = t & 63;
  int lr = l >> 2;
  int lc = (((l & 3) ^ (lr & 3)) * 8);  // swizzled source chunk
  int quad = l >> 4, ln = l & 15;
  int wm = w >> 1, wn = w & 1;
  int rdoff = ((quad ^ (ln & 3)) * 8);  // swizzled read offset

  int Keff = (MODE == 2) ? (by + 1) * 128 : K;

  f32x4 acc[4][4];
#pragma unroll
  for (int i = 0; i < 4; i++)
#pragma unroll
    for (int j = 0; j < 4; j++) acc[i][j] = f32x4{0.f, 0.f, 0.f, 0.f};

  const bf16* a_base = As + (wm * 64 + ln) * 32 + rdoff;
  const bf16* b_base = Bs + (wn * 64 + ln) * 32 + rdoff;
  long arow0 = (long)(w * 16 + lr);

  for (int k0 = 0; k0 < Keff; k0 += 64) {
#pragma unroll
    for (int kk = 0; kk < 2; kk++) {
      int kc = k0 + kk * 32 + lc;
      gload_lds16(A + arow0 * lda + kc, As + kk * 4096 + w * 512);
      gload_lds16(A + (arow0 + 64) * lda + kc, As + kk * 4096 + 2048 + w * 512);
      gload_lds16(Bp + arow0 * ldb + kc, Bs + kk * 4096 + w * 512);
      gload_lds16(Bp + (arow0 + 64) * ldb + kc, Bs + kk * 4096 + 2048 + w * 512);
    }
    asm volatile("s_waitcnt vmcnt(0)" ::: "memory");
    __syncthreads();

#pragma unroll
    for (int kk = 0; kk < 2; kk++) {
      bf16x8 af[4], bfr[4];
#pragma unroll
      for (int i = 0; i < 4; i++) {
        af[i] = *(const bf16x8*)(a_base + kk * 4096 + i * 512);
        bfr[i] = *(const bf16x8*)(b_base + kk * 4096 + i * 512);
      }
#pragma unroll
      for (int i = 0; i < 4; i++)
#pragma unroll
        for (int j = 0; j < 4; j++)
          acc[i][j] = __builtin_amdgcn_mfma_f32_16x16x32_bf16(
              af[i], bfr[j], acc[i][j], 0, 0, 0);
    }
    __syncthreads();
  }

  // epilogue: within each 16x16 tile, C row = quad*4 + r, col = ln
  if (MODE == 0) {
    if (vTp && n0 >= 2048) {
      // V-region: bounce through LDS, write transposed to vT[b][d][s].
      int d0 = (int)n0 - 2048;
      int b = (int)(m0 >> 11);
      int s0 = (int)(m0 & 2047);
#pragma unroll
      for (int i = 0; i < 4; i++) {
        int sb = wm * 64 + i * 16 + quad * 4;
#pragma unroll
        for (int j = 0; j < 4; j++) {
          int d = wn * 64 + j * 16 + ln;
          float bv_ = bias[n0 + d];
#pragma unroll
          for (int r = 0; r < 4; r++)
            smem[d * 128 + ((sb + r) ^ (ln << 3))] = (bf16)(acc[i][j][r] + bv_);
        }
      }
      __syncthreads();
      int d = t >> 1, h = t & 1;
      bf16* dst = vTp + (long)b * DD * SS + (long)(d0 + d) * SS + s0 + h * 64;
#pragma unroll
      for (int j = 0; j < 8; j++) {
        int sbase = h * 64 + j * 8;
        bf16x8 v = *(const bf16x8*)(smem + d * 128 + (sbase ^ ((d & 15) << 3)));
        *(bf16x8*)(dst + j * 8) = v;
      }
    } else {
      bf16* C = (bf16*)Cg + (long)bz * sCb + m0 * ldc + n0;
#pragma unroll
      for (int i = 0; i < 4; i++) {
        int rb = wm * 64 + i * 16 + quad * 4;
#pragma unroll
        for (int j = 0; j < 4; j++) {
          int col = wn * 64 + j * 16 + ln;
          float bv_ = bias ? bias[n0 + col] : 0.f;
#pragma unroll
          for (int r = 0; r < 4; r++)
            C[(long)(rb + r) * ldc + col] = (bf16)(acc[i][j][r] + bv_);
        }
      }
    }
  } else if (MODE == 1) {
    // fused-exp epilogue: p~ = exp(scale*acc), 0 above diagonal.
    // store to smem[row*128 + (col ^ ((row&15)<<3))] (chunk-slot swizzle)
#pragma unroll
    for (int i = 0; i < 4; i++) {
      int rb = wm * 64 + i * 16 + quad * 4;
#pragma unroll
      for (int j = 0; j < 4; j++) {
        int col = wn * 64 + j * 16 + ln;
#pragma unroll
        for (int r = 0; r < 4; r++) {
          int row = rb + r;
          float p = 0.f;
          if (n0 + col <= m0 + row) p = __expf(acc[i][j][r] * scale);
          smem[row * 128 + (col ^ ((row & 15) << 3))] = (bf16)p;
        }
      }
    }
    __syncthreads();
    // copy-out: thread t -> row t>>1, 64-col half t&1; sum bf16-rounded p~
    int row = t >> 1, h = t & 1;
    bf16* P = (bf16*)Cg + (long)bz * sCb + (m0 + row) * ldc + n0;
    float rsum = 0.f;
#pragma unroll
    for (int jj = 0; jj < 8; jj++) {
      int p8 = h * 8 + jj;              // 16B chunk index within 128 cols
      int slot = p8 ^ (row & 15);
      bf16x8 v = *(const bf16x8*)(smem + row * 128 + slot * 8);
#pragma unroll
      for (int e = 0; e < 8; e++) rsum += (float)v[e];
      *(bf16x8*)(P + p8 * 8) = v;
    }
    atomicAdd(&rowsums[(long)bz * SS + m0 + row], rsum);
  } else {
    // MODE 2: out = (P~ @ V) / rowsum
    float* C = (float*)Cg + (long)bz * sCb + m0 * ldc + n0;
    const float* rs = rowsums + (long)bz * SS + m0;
#pragma unroll
    for (int i = 0; i < 4; i++) {
      int rb = wm * 64 + i * 16 + quad * 4;
      float inv[4];
#pragma unroll
      for (int r = 0; r < 4; r++) inv[r] = 1.f / rs[rb + r];
#pragma unroll
      for (int j = 0; j < 4; j++) {
        int col = wn * 64 + j * 16 + ln;
#pragma unroll
        for (int r = 0; r < 4; r++)
          C[(long)(rb + r) * ldc + col] = acc[i][j][r] * inv[r];
      }
    }
  }
}

extern "C" void kernel_launch(void* const* d_in, const int* in_sizes, int n_in,
                              void* d_out, int out_size, void* d_ws,
                              size_t ws_size, hipStream_t stream) {
  const float* x = (const float*)d_in[0];
  const float* R = (const float*)d_in[1];
  const float* E = (const float*)d_in[2];
  const float* Wq = (const float*)d_in[3];
  const float* bq = (const float*)d_in[4];
  const float* Wk = (const float*)d_in[5];
  const float* bk = (const float*)d_in[6];
  const float* Wv = (const float*)d_in[7];
  const float* bv = (const float*)d_in[8];
  float* out = (float*)d_out;

  char* ws = (char*)d_ws;
  // Layout (128 MiB total, NO aliasing):
  //   qkv     @ 0       : 8192*3072 bf16 (V cols unused)  = 48 MiB
  //   vT      @ 48 MiB  : 4*1024*2048 bf16                = 16 MiB
  //   probs   @ 64 MiB  : 4*2048*2048 bf16 (unnormalized) = 32 MiB
  //   rowsums @ 96 MiB  : 8192 f32                        = 32 KiB
  //   prep    @ 97 MiB  : xb 16 | Rb 2 | Eb 2 | WqT 2 | WkT 2 | wcat 6 | bias
  bf16* qkv = (bf16*)ws;
  bf16* vT = (bf16*)(ws + 50331648);
  bf16* probs = (bf16*)(ws + 67108864);
  float* rowsums = (float*)(ws + 100663296);
  char* sr = ws + 101711872;
  bf16* xb = (bf16*)sr;                   // 16 MiB
  bf16* Rb = (bf16*)(sr + 16777216);      // 2 MiB
  bf16* Eb = Rb + 1024 * 1024;            // 2 MiB
  bf16* WqT = (bf16*)(sr + 20971520);     // 2 MiB
  bf16* WkT = WqT + 1024 * 1024;          // 2 MiB
  bf16* wcat = (bf16*)(sr + 25165824);    // 6 MiB (Wq'|Wk'|Wv)
  float* bias = (float*)(sr + 31457280);  // 12 KiB

  // 1) all preprocessing + rowsum zeroing: 1 dispatch
  prep_all<<<16416, 256, 0, stream>>>(x, R, E, Wv, Wq, Wk, bq, bk, bv, xb, Rb,
                                      Eb, wcat + 2048 * DD, WqT, WkT, bias,
                                      rowsums);

  // 2) fold weights (batched bz=2): Wq' = R@Wq ; Wk' = E@Wk
  gemm_bt<0><<<dim3(8, 8, 2), 256, 0, stream>>>(
      Rb, DD, 1024 * 1024, WqT, DD, 1024 * 1024, wcat, DD, 1024 * 1024,
      nullptr, 1.f, DD, nullptr, nullptr);

  // 3) fused QKV (M=8192, N=3072, K=1024); V-tiles written transposed to vT
  gemm_bt<0><<<dim3(24, 64, 1), 256, 0, stream>>>(xb, DD, 0, wcat, DD, 0, qkv,
                                                  3072, 0, bias, 1.f, DD, vT,
                                                  nullptr);

  // 4) causal scores + fused exp -> bf16 probs + row sums (136 tri tiles)
  gemm_bt<1><<<dim3(136, 1, BB), 256, 0, stream>>>(
      qkv, 3072, (long)SS * 3072, qkv + 1024, 3072, (long)SS * 3072, probs,
      SS, (long)SS * SS, nullptr, 0.03125f, DD, nullptr, rowsums);

  // 5) out = (P~ @ V) / rowsum : K truncated causally, long strips first
  gemm_bt<2><<<dim3(8, 16, BB), 256, 0, stream>>>(
      probs, SS, (long)SS * SS, vT, SS, (long)DD * SS, out,
      DD, (long)SS * DD, nullptr, 1.f, SS, nullptr, rowsums);
}